// Round 1
// baseline (905.877 us; speedup 1.0000x reference)
//
#include <hip/hip_runtime.h>
#include <hip/hip_bf16.h>

// ---------------------------------------------------------------------------
// TransformerBlock on MI355X (gfx950), bf16 MFMA pipeline.
//   LN1 -> QKV gemm -> flash-ish MFMA attention -> proj gemm (+x residual)
//   -> LN2 -> FFN1 gemm (relu) -> FFN2 gemm (+residual)
// All GEMMs: m97-ladder structure (128x128 tile, BK=32, global_load_lds w=16,
// mfma_f32_16x16x32_bf16, A[M][K] x Bt[N][K]).
// ---------------------------------------------------------------------------

typedef __attribute__((ext_vector_type(8))) short bf16x8;
typedef __attribute__((ext_vector_type(4))) float f32x4;
typedef unsigned short u16;
typedef unsigned int u32;

#define MFMA16(a, b, c) __builtin_amdgcn_mfma_f32_16x16x32_bf16((a), (b), (c), 0, 0, 0)

__device__ __forceinline__ void gl2lds16(const void* g, void* l) {
  __builtin_amdgcn_global_load_lds((const __attribute__((address_space(1))) u32*)g,
                                   (__attribute__((address_space(3))) u32*)l, 16, 0, 0);
}

__device__ __forceinline__ u16 f2bf(float f) {
  __hip_bfloat16 h = __float2bfloat16(f);
  return *(u16*)&h;
}
__device__ __forceinline__ float bf2f(u16 u) {
  __hip_bfloat16 h;
  *(u16*)&h = u;
  return __bfloat162float(h);
}

// ---------------------------------------------------------------------------
// GEMM: out[M][N] = A[M][K] (bf16) * Bt[N][K]^T (bf16)  [+bias] [relu] [+res]
// ---------------------------------------------------------------------------
template <int HAS_BIAS, int HAS_RES, int RELU, int OUT_BF16>
__global__ __launch_bounds__(256) void gemm_bt(const u16* __restrict__ A,
                                               const u16* __restrict__ Bt,
                                               const float* __restrict__ bias,
                                               const float* res, void* outp,
                                               int M, int N, int K) {
  __shared__ __attribute__((aligned(16))) u16 As[128 * 32];
  __shared__ __attribute__((aligned(16))) u16 Bs[128 * 32];
  const int m0 = blockIdx.y * 128, n0 = blockIdx.x * 128;
  const int w = threadIdx.x >> 6, l = threadIdx.x & 63;
  const int lm = l & 15, quad = l >> 4;
  const int wm = (w >> 1) * 64, wn = (w & 1) * 64;
  f32x4 acc[4][4];
#pragma unroll
  for (int i = 0; i < 4; ++i)
#pragma unroll
    for (int j = 0; j < 4; ++j) acc[i][j] = 0.f;

  for (int k0 = 0; k0 < K; k0 += 32) {
#pragma unroll
    for (int j = 0; j < 2; ++j) {
      int ci = w * 128 + j * 64 + l;       // 16B-chunk index in tile
      int row = ci >> 2, cc = ci & 3;      // 4 chunks per 32-elem row
      gl2lds16(A + (size_t)(m0 + row) * K + k0 + cc * 8, &As[(w * 128 + j * 64) * 8]);
      gl2lds16(Bt + (size_t)(n0 + row) * K + k0 + cc * 8, &Bs[(w * 128 + j * 64) * 8]);
    }
    __syncthreads();
    bf16x8 af[4], bfb[4];
#pragma unroll
    for (int i = 0; i < 4; ++i)
      af[i] = *(const bf16x8*)&As[(wm + i * 16 + lm) * 32 + quad * 8];
#pragma unroll
    for (int j = 0; j < 4; ++j)
      bfb[j] = *(const bf16x8*)&Bs[(wn + j * 16 + lm) * 32 + quad * 8];
#pragma unroll
    for (int i = 0; i < 4; ++i)
#pragma unroll
      for (int j = 0; j < 4; ++j) acc[i][j] = MFMA16(af[i], bfb[j], acc[i][j]);
    __syncthreads();
  }
  // Epilogue. C/D layout (m89-verified): col = lane&15, row = quad*4 + reg.
#pragma unroll
  for (int i = 0; i < 4; ++i) {
#pragma unroll
    for (int j = 0; j < 4; ++j) {
      int col = n0 + wn + j * 16 + lm;
      float bs = HAS_BIAS ? bias[col] : 0.f;
#pragma unroll
      for (int r = 0; r < 4; ++r) {
        int row = m0 + wm + i * 16 + quad * 4 + r;
        float v = acc[i][j][r] + bs;
        if (RELU) v = fmaxf(v, 0.f);
        if (HAS_RES) v += res[(size_t)row * N + col];
        if (OUT_BF16)
          ((u16*)outp)[(size_t)row * N + col] = f2bf(v);
        else
          ((float*)outp)[(size_t)row * N + col] = v;
      }
    }
  }
}

// ---------------------------------------------------------------------------
// LayerNorm: one wave per 384-elem row, 4 rows per block.
// ---------------------------------------------------------------------------
__global__ __launch_bounds__(256) void ln_kernel(const float* __restrict__ x,
                                                 const float* __restrict__ g,
                                                 const float* __restrict__ be,
                                                 u16* __restrict__ out) {
  int row = blockIdx.x * 4 + (threadIdx.x >> 6);
  int l = threadIdx.x & 63;
  const float* xr = x + (size_t)row * 384;
  float v[6];
  float s = 0.f;
#pragma unroll
  for (int i = 0; i < 6; ++i) {
    v[i] = xr[l + i * 64];
    s += v[i];
  }
#pragma unroll
  for (int o = 1; o < 64; o <<= 1) s += __shfl_xor(s, o, 64);
  float mu = s * (1.f / 384.f);
  float var = 0.f;
#pragma unroll
  for (int i = 0; i < 6; ++i) {
    float d = v[i] - mu;
    var += d * d;
  }
#pragma unroll
  for (int o = 1; o < 64; o <<= 1) var += __shfl_xor(var, o, 64);
  float rs = rsqrtf(var * (1.f / 384.f) + 1e-5f);
  u16* orow = out + (size_t)row * 384;
#pragma unroll
  for (int i = 0; i < 6; ++i)
    orow[l + i * 64] = f2bf((v[i] - mu) * rs * g[l + i * 64] + be[l + i * 64]);
}

// ---------------------------------------------------------------------------
// Weight transposes (fp32 -> bf16, [K][N] -> [N][K]); tiny, run once per call.
// ---------------------------------------------------------------------------
__global__ void wT_kernel(const float* __restrict__ in, u16* __restrict__ out,
                          int K, int N) {
  int idx = blockIdx.x * 256 + threadIdx.x;
  if (idx >= K * N) return;
  int n = idx / K, k = idx - n * K;
  out[idx] = f2bf(in[(size_t)k * N + n]);
}

// Wq[h][c][d] -> out[(h*64+d)][c]
__global__ void qkvT_kernel(const float* __restrict__ W, u16* __restrict__ out) {
  int idx = blockIdx.x * 256 + threadIdx.x;
  if (idx >= 6 * 384 * 64) return;
  int r = idx / 384;
  int c = idx - r * 384;
  int h = r >> 6, d = r & 63;
  out[idx] = f2bf(W[(size_t)(h * 384 + c) * 64 + d]);
}

// ---------------------------------------------------------------------------
// Attention: block = (b, h), one 64-row Q tile (TQ = tile index, templated so
// register arrays stay statically indexed). S kept in MFMA C-layout registers;
// softmax via width-16 shuffles; P and Vt round-trip through LDS (XOR-8
// swizzle to break the stride-512B bank aliasing on b128 reads).
// ---------------------------------------------------------------------------
template <int TQ>
__global__ __launch_bounds__(256) void attn_kernel(const u16* __restrict__ qkv,
                                                   u16* __restrict__ attnout) {
  constexpr int NFULL = (TQ + 1) * 64;   // causal: cols 0..NFULL-1
  constexpr int NJ = NFULL / 16;
  constexpr int KSTEPS = NFULL / 32;
  int bh = blockIdx.x;
  int h = bh % 6, b = bh / 6;
  int tid = threadIdx.x;
  int w = tid >> 6, l = tid & 63;
  int lm = l & 15, quad = l >> 4;

  __shared__ __attribute__((aligned(16))) unsigned char smx[65536];
  u16* Qs = (u16*)smx;             // [64][72]   phase 1 (stride 72 = 144B, 16B-mult)
  u16* Ks = (u16*)(smx + 9216);    // [256][72]  phase 1
  u16* P = (u16*)smx;              // [64][256]  phase 2 (aliases Qs+Ks head)
  u16* Vt = (u16*)(smx + 32768);   // [64][256]  phase 2 (aliases Ks tail)

  const u16* Qg = qkv + ((size_t)(b * 256 + TQ * 64)) * 1152 + h * 64;
  const u16* Kg = qkv + ((size_t)(b * 256)) * 1152 + 384 + h * 64;
  const u16* Vg = qkv + ((size_t)(b * 256)) * 1152 + 768 + h * 64;

  // Stage Q (pre-scaled by 1/sqrt(64)) and K.
  for (int i = tid; i < 64 * 64; i += 256) {
    int r = i >> 6, d = i & 63;
    Qs[r * 72 + d] = f2bf(0.125f * bf2f(Qg[(size_t)r * 1152 + d]));
  }
  for (int i = tid; i < NFULL * 64; i += 256) {
    int r = i >> 6, d = i & 63;
    Ks[r * 72 + d] = Kg[(size_t)r * 1152 + d];
  }
  __syncthreads();

  // S = Q K^T ; wave w owns query rows [w*16, w*16+16).
  f32x4 sacc[NJ];
#pragma unroll
  for (int jt = 0; jt < NJ; ++jt) sacc[jt] = 0.f;
#pragma unroll
  for (int kk = 0; kk < 2; ++kk) {
    bf16x8 aq = *(const bf16x8*)&Qs[(w * 16 + lm) * 72 + kk * 32 + quad * 8];
#pragma unroll
    for (int jt = 0; jt < NJ; ++jt) {
      bf16x8 bk = *(const bf16x8*)&Ks[(jt * 16 + lm) * 72 + kk * 32 + quad * 8];
      sacc[jt] = MFMA16(aq, bk, sacc[jt]);
    }
  }
  __syncthreads();  // Qs/Ks reads done; P/Vt writes may begin.

  // Softmax in registers. Lane (quad,lm) reg holds S[w*16+quad*4+reg][jt*16+lm].
  int trow = TQ * 64 + w * 16 + quad * 4;  // + reg = global query index
  float inv_l[4];
#pragma unroll
  for (int reg = 0; reg < 4; ++reg) {
    float m_ = -3.0e38f;
#pragma unroll
    for (int jt = 0; jt < NJ; ++jt) {
      int col = jt * 16 + lm;
      if (col <= trow + reg) m_ = fmaxf(m_, sacc[jt][reg]);
    }
#pragma unroll
    for (int o = 1; o < 16; o <<= 1) m_ = fmaxf(m_, __shfl_xor(m_, o, 16));
    float s_ = 0.f;
#pragma unroll
    for (int jt = 0; jt < NJ; ++jt) {
      int col = jt * 16 + lm;
      float p = (col <= trow + reg) ? __expf(sacc[jt][reg] - m_) : 0.f;
      sacc[jt][reg] = p;
      s_ += p;
    }
#pragma unroll
    for (int o = 1; o < 16; o <<= 1) s_ += __shfl_xor(s_, o, 16);
    inv_l[reg] = 1.f / s_;
  }
  // Write P (bf16, XOR-8 swizzled rows).
#pragma unroll
  for (int jt = 0; jt < NJ; ++jt) {
#pragma unroll
    for (int reg = 0; reg < 4; ++reg) {
      int m = w * 16 + quad * 4 + reg;
      int col = jt * 16 + lm;
      P[m * 256 + (col ^ ((m & 7) * 8))] = f2bf(sacc[jt][reg] * inv_l[reg]);
    }
  }
  // Stage V transposed (coalesced global read, swizzled LDS write).
  for (int i = tid; i < NFULL * 64; i += 256) {
    int s = i >> 6, d = i & 63;
    Vt[d * 256 + (s ^ ((d & 7) * 8))] = Vg[(size_t)s * 1152 + d];
  }
  __syncthreads();

  // O = P V ; wave w reads back its own 16 query rows.
  f32x4 oacc[4];
#pragma unroll
  for (int jt = 0; jt < 4; ++jt) oacc[jt] = 0.f;
#pragma unroll
  for (int ks = 0; ks < KSTEPS; ++ks) {
    int m = w * 16 + lm;
    int kc = ks * 32 + quad * 8;
    bf16x8 ap = *(const bf16x8*)&P[m * 256 + (kc ^ ((m & 7) * 8))];
#pragma unroll
    for (int jt = 0; jt < 4; ++jt) {
      int n = jt * 16 + lm;
      bf16x8 bv = *(const bf16x8*)&Vt[n * 256 + (kc ^ ((n & 7) * 8))];
      oacc[jt] = MFMA16(ap, bv, oacc[jt]);
    }
  }
  u16* Og = attnout + ((size_t)(b * 256 + TQ * 64)) * 384 + h * 64;
#pragma unroll
  for (int jt = 0; jt < 4; ++jt)
#pragma unroll
    for (int r = 0; r < 4; ++r)
      Og[(size_t)(w * 16 + quad * 4 + r) * 384 + jt * 16 + lm] = f2bf(oacc[jt][r]);
}

// ---------------------------------------------------------------------------
extern "C" void kernel_launch(void* const* d_in, const int* in_sizes, int n_in,
                              void* d_out, int out_size, void* d_ws, size_t ws_size,
                              hipStream_t stream) {
  const float* x = (const float*)d_in[0];
  const float* Wq = (const float*)d_in[1];
  const float* Wk = (const float*)d_in[2];
  const float* Wv = (const float*)d_in[3];
  const float* Wp = (const float*)d_in[4];
  const float* bp = (const float*)d_in[5];
  const float* W1 = (const float*)d_in[6];
  const float* b1 = (const float*)d_in[7];
  const float* W2 = (const float*)d_in[8];
  const float* b2 = (const float*)d_in[9];
  const float* g1 = (const float*)d_in[10];
  const float* be1 = (const float*)d_in[11];
  const float* g2 = (const float*)d_in[12];
  const float* be2 = (const float*)d_in[13];
  float* out = (float*)d_out;

  const int BT = 65536;  // 256*256
  char* ws = (char*)d_ws;
  // Workspace layout (ff1 aliases qkv+attnout, dead by FFN1):
  u16* qkv = (u16*)(ws);                          // [BT][1152] bf16  150,994,944 B
  u16* attnout = (u16*)(ws + 150994944);          // [BT][384]  bf16   50,331,648 B
  u16* ff1 = (u16*)(ws);                          // [BT][1536] bf16  201,326,592 B
  u16* h = (u16*)(ws + 201326592);                // [BT][384]  bf16   50,331,648 B
  u16* WqkvT = (u16*)(ws + 251658240);            // [1152][384]
  u16* WpT = (u16*)(ws + 252542976);              // [384][384]
  u16* W1T = (u16*)(ws + 252837888);              // [1536][384]
  u16* W2T = (u16*)(ws + 254017536);              // [384][1536]

  // Weight transposes (bf16 cast), tiny.
  qkvT_kernel<<<576, 256, 0, stream>>>(Wq, WqkvT);
  qkvT_kernel<<<576, 256, 0, stream>>>(Wk, WqkvT + 384 * 384);
  qkvT_kernel<<<576, 256, 0, stream>>>(Wv, WqkvT + 2 * 384 * 384);
  wT_kernel<<<576, 256, 0, stream>>>(Wp, WpT, 384, 384);
  wT_kernel<<<2304, 256, 0, stream>>>(W1, W1T, 384, 1536);
  wT_kernel<<<2304, 256, 0, stream>>>(W2, W2T, 1536, 384);

  // LN1: x -> h (bf16)
  ln_kernel<<<BT / 4, 256, 0, stream>>>(x, g1, be1, h);
  // QKV: h @ Wqkv -> qkv [BT][1152]
  gemm_bt<0, 0, 0, 1><<<dim3(9, 512), 256, 0, stream>>>(h, WqkvT, nullptr, nullptr,
                                                        qkv, BT, 1152, 384);
  // Attention (4 Q-tile variants, 1536 (b,h) blocks each)
  attn_kernel<0><<<1536, 256, 0, stream>>>(qkv, attnout);
  attn_kernel<1><<<1536, 256, 0, stream>>>(qkv, attnout);
  attn_kernel<2><<<1536, 256, 0, stream>>>(qkv, attnout);
  attn_kernel<3><<<1536, 256, 0, stream>>>(qkv, attnout);
  // Proj + bias + residual(x) -> d_out (fp32)
  gemm_bt<1, 1, 0, 0><<<dim3(3, 512), 256, 0, stream>>>(attnout, WpT, bp, x, out,
                                                        BT, 384, 384);
  // LN2: d_out -> h (bf16)
  ln_kernel<<<BT / 4, 256, 0, stream>>>(out, g2, be2, h);
  // FFN1 + bias + relu -> ff1 (bf16)
  gemm_bt<1, 0, 1, 1><<<dim3(12, 512), 256, 0, stream>>>(h, W1T, b1, nullptr, ff1,
                                                         BT, 1536, 384);
  // FFN2 + bias + residual(d_out) -> d_out (fp32)
  gemm_bt<1, 1, 0, 0><<<dim3(3, 512), 256, 0, stream>>>(ff1, W2T, b2, out, out,
                                                        BT, 384, 1536);
}

// Round 2
// 811.172 us; speedup vs baseline: 1.1168x; 1.1168x over previous
//
#include <hip/hip_runtime.h>
#include <hip/hip_bf16.h>

// ---------------------------------------------------------------------------
// TransformerBlock on MI355X (gfx950), bf16 MFMA pipeline. Round 1:
//  - GEMM: BK=64, XOR-swizzled LDS (conflict-free b128 reads, gl2lds-legal),
//    XCD-chunked 1-D grid swizzle (same-A-tile blocks share an XCD L2).
//  - Attention: one merged kernel (TQ = blockIdx.x), vectorized staging,
//    1/sqrt(d) folded into exp, head-major qkv slabs [3][H][BT][64].
//  - LN: float2-vectorized loads, packed u32 bf16 stores.
// ---------------------------------------------------------------------------

typedef __attribute__((ext_vector_type(8))) short bf16x8;
typedef __attribute__((ext_vector_type(4))) float f32x4;
typedef unsigned short u16;
typedef unsigned int u32;

#define MFMA16(a, b, c) __builtin_amdgcn_mfma_f32_16x16x32_bf16((a), (b), (c), 0, 0, 0)

__device__ __forceinline__ void gl2lds16(const void* g, void* l) {
  __builtin_amdgcn_global_load_lds((const __attribute__((address_space(1))) u32*)g,
                                   (__attribute__((address_space(3))) u32*)l, 16, 0, 0);
}

__device__ __forceinline__ u16 f2bf(float f) {
  __hip_bfloat16 h = __float2bfloat16(f);
  return *(u16*)&h;
}
__device__ __forceinline__ float bf2f(u16 u) {
  __hip_bfloat16 h;
  *(u16*)&h = u;
  return __bfloat162float(h);
}
__device__ __forceinline__ u32 pack2(float lo, float hi) {
  return (u32)f2bf(lo) | ((u32)f2bf(hi) << 16);
}

// ---------------------------------------------------------------------------
// GEMM: out[M][N] = A[M][K] (bf16) * Bt[N][K]^T (bf16)  [+bias] [relu] [+res]
// OUT_MODE: 0 = fp32 row-major, 1 = bf16 row-major, 2 = bf16 qkv slabs
// Grid is 1-D (gx*gy blocks, gy multiple of 8); XCD swizzle: xcd = bid&7 gets
// a contiguous M-chunk, n varies fastest within it -> A-tile reuse in one L2.
// BK=64; LDS tile stored as 16B chunks with slot cs = cg ^ (row&7) so that
// (a) gl2lds wave-linear destination holds and (b) ds_read_b128 frag reads
// land 2-way per bank group (free).
// ---------------------------------------------------------------------------
template <int HAS_BIAS, int HAS_RES, int RELU, int OUT_MODE>
__global__ __launch_bounds__(256) void gemm_bt(const u16* __restrict__ A,
                                               const u16* __restrict__ Bt,
                                               const float* __restrict__ bias,
                                               const float* res, void* outp,
                                               int M, int N, int K, int gx) {
  __shared__ __attribute__((aligned(16))) u16 As[128 * 64];
  __shared__ __attribute__((aligned(16))) u16 Bs[128 * 64];
  const int bid = blockIdx.x;
  const int s = bid >> 3, xcd = bid & 7;
  const int gy8 = gridDim.x / (8 * gx);
  const int nI = s % gx, mC = s / gx;
  const int m0 = (xcd * gy8 + mC) * 128, n0 = nI * 128;
  const int w = threadIdx.x >> 6, l = threadIdx.x & 63;
  const int lm = l & 15, quad = l >> 4;
  const int wm = (w >> 1) * 64, wn = (w & 1) * 64;
  f32x4 acc[4][4];
#pragma unroll
  for (int i = 0; i < 4; ++i)
#pragma unroll
    for (int j = 0; j < 4; ++j) acc[i][j] = 0.f;

  for (int k0 = 0; k0 < K; k0 += 64) {
#pragma unroll
    for (int j = 0; j < 4; ++j) {
      int ell = (w * 4 + j) * 64 + l;  // 16B-chunk slot in [0,1024)
      int row = ell >> 3;              // 8 chunks per 64-elem row
      int cs = ell & 7;
      int cg = cs ^ (row & 7);         // global chunk this slot holds
      gl2lds16(A + (size_t)(m0 + row) * K + k0 + cg * 8, &As[(w * 4 + j) * 64 * 8]);
      gl2lds16(Bt + (size_t)(n0 + row) * K + k0 + cg * 8, &Bs[(w * 4 + j) * 64 * 8]);
    }
    __syncthreads();
#pragma unroll
    for (int ks = 0; ks < 2; ++ks) {
      bf16x8 af[4], bfb[4];
#pragma unroll
      for (int i = 0; i < 4; ++i) {
        int r = wm + i * 16 + lm;
        af[i] = *(const bf16x8*)&As[r * 64 + (((ks * 4 + quad) ^ (r & 7)) * 8)];
      }
#pragma unroll
      for (int j = 0; j < 4; ++j) {
        int r = wn + j * 16 + lm;
        bfb[j] = *(const bf16x8*)&Bs[r * 64 + (((ks * 4 + quad) ^ (r & 7)) * 8)];
      }
#pragma unroll
      for (int i = 0; i < 4; ++i)
#pragma unroll
        for (int j = 0; j < 4; ++j) acc[i][j] = MFMA16(af[i], bfb[j], acc[i][j]);
    }
    __syncthreads();
  }
  // Epilogue. C/D layout (m89-verified): col = lane&15, row = quad*4 + reg.
#pragma unroll
  for (int i = 0; i < 4; ++i) {
#pragma unroll
    for (int j = 0; j < 4; ++j) {
      int col = n0 + wn + j * 16 + lm;
      float bs = HAS_BIAS ? bias[col] : 0.f;
#pragma unroll
      for (int r = 0; r < 4; ++r) {
        int row = m0 + wm + i * 16 + quad * 4 + r;
        float v = acc[i][j][r] + bs;
        if (RELU) v = fmaxf(v, 0.f);
        if (HAS_RES) v += res[(size_t)row * N + col];
        if (OUT_MODE == 0) {
          ((float*)outp)[(size_t)row * N + col] = v;
        } else if (OUT_MODE == 1) {
          ((u16*)outp)[(size_t)row * N + col] = f2bf(v);
        } else {  // qkv slab layout [sel*6+h][BT][64]
          int sel = col / 384;
          int rem = col - sel * 384;
          int hh = rem >> 6, dd = rem & 63;
          ((u16*)outp)[((size_t)(sel * 6 + hh) * 65536 + row) * 64 + dd] = f2bf(v);
        }
      }
    }
  }
}

// ---------------------------------------------------------------------------
// LayerNorm: one wave per 384-elem row, 4 rows per block, 6 elems/lane.
// ---------------------------------------------------------------------------
__global__ __launch_bounds__(256) void ln_kernel(const float* __restrict__ x,
                                                 const float* __restrict__ g,
                                                 const float* __restrict__ be,
                                                 u16* __restrict__ out) {
  int row = blockIdx.x * 4 + (threadIdx.x >> 6);
  int l = threadIdx.x & 63;
  const float2* xr = (const float2*)(x + (size_t)row * 384 + l * 6);
  float2 t0 = xr[0], t1 = xr[1], t2 = xr[2];
  float v[6] = {t0.x, t0.y, t1.x, t1.y, t2.x, t2.y};
  float s = 0.f;
#pragma unroll
  for (int i = 0; i < 6; ++i) s += v[i];
#pragma unroll
  for (int o = 1; o < 64; o <<= 1) s += __shfl_xor(s, o, 64);
  float mu = s * (1.f / 384.f);
  float var = 0.f;
#pragma unroll
  for (int i = 0; i < 6; ++i) {
    float d = v[i] - mu;
    var += d * d;
  }
#pragma unroll
  for (int o = 1; o < 64; o <<= 1) var += __shfl_xor(var, o, 64);
  float rs = rsqrtf(var * (1.f / 384.f) + 1e-5f);
  const float2* gg = (const float2*)(g + l * 6);
  const float2* bb = (const float2*)(be + l * 6);
  float2 g0 = gg[0], g1 = gg[1], g2 = gg[2];
  float2 b0 = bb[0], b1 = bb[1], b2 = bb[2];
  float gv[6] = {g0.x, g0.y, g1.x, g1.y, g2.x, g2.y};
  float bv[6] = {b0.x, b0.y, b1.x, b1.y, b2.x, b2.y};
  float o_[6];
#pragma unroll
  for (int i = 0; i < 6; ++i) o_[i] = (v[i] - mu) * rs * gv[i] + bv[i];
  u32* orow = (u32*)(out + (size_t)row * 384 + l * 6);
  orow[0] = pack2(o_[0], o_[1]);
  orow[1] = pack2(o_[2], o_[3]);
  orow[2] = pack2(o_[4], o_[5]);
}

// ---------------------------------------------------------------------------
// Weight transposes (fp32 -> bf16, [K][N] -> [N][K]); tiny, run once per call.
// ---------------------------------------------------------------------------
__global__ void wT_kernel(const float* __restrict__ in, u16* __restrict__ out,
                          int K, int N) {
  int idx = blockIdx.x * 256 + threadIdx.x;
  if (idx >= K * N) return;
  int n = idx / K, k = idx - n * K;
  out[idx] = f2bf(in[(size_t)k * N + n]);
}

// Wq[h][c][d] -> out[(h*64+d)][c]
__global__ void qkvT_kernel(const float* __restrict__ W, u16* __restrict__ out) {
  int idx = blockIdx.x * 256 + threadIdx.x;
  if (idx >= 6 * 384 * 64) return;
  int r = idx / 384;
  int c = idx - r * 384;
  int h = r >> 6, d = r & 63;
  out[idx] = f2bf(W[(size_t)(h * 384 + c) * 64 + d]);
}

// ---------------------------------------------------------------------------
// Attention. qkv slabs: Q = slab h, K = slab 6+h, V = slab 12+h, each
// [65536][64]. One merged kernel, TQ = blockIdx.x (switch to 4 template
// bodies so register arrays stay statically indexed).
// ---------------------------------------------------------------------------
template <int TQ>
__device__ __forceinline__ void attn_body(const u16* __restrict__ qkv,
                                          u16* __restrict__ attnout,
                                          unsigned char* smx) {
  constexpr int NFULL = (TQ + 1) * 64;  // causal: cols 0..NFULL-1
  constexpr int NJ = NFULL / 16;
  constexpr int KSTEPS = NFULL / 32;
  int bh = blockIdx.y;
  int h = bh % 6, b = bh / 6;
  int tid = threadIdx.x;
  int w = tid >> 6, l = tid & 63;
  int lm = l & 15, quad = l >> 4;

  u16* Qs = (u16*)smx;            // [64][72]   phase 1
  u16* Ks = (u16*)(smx + 9216);   // [256][72]  phase 1
  u16* P = (u16*)smx;             // [64][256]  phase 2 (aliases Qs + Ks head)
  u16* Vt = (u16*)(smx + 32768);  // [64][256]  phase 2 (aliases Ks tail)

  const u16* Qg = qkv + ((size_t)h * 65536 + b * 256 + TQ * 64) * 64;
  const u16* Kg = qkv + ((size_t)(6 + h) * 65536 + b * 256) * 64;
  const u16* Vg = qkv + ((size_t)(12 + h) * 65536 + b * 256) * 64;

  // Stage Q and K (vectorized 16B copies; rows padded to 72 in LDS).
  for (int i = tid; i < 64 * 8; i += 256) {
    int r = i >> 3, cs = i & 7;
    *(bf16x8*)&Qs[r * 72 + cs * 8] = *(const bf16x8*)&Qg[r * 64 + cs * 8];
  }
  for (int i = tid; i < NFULL * 8; i += 256) {
    int r = i >> 3, cs = i & 7;
    *(bf16x8*)&Ks[r * 72 + cs * 8] = *(const bf16x8*)&Kg[r * 64 + cs * 8];
  }
  __syncthreads();

  // S = Q K^T ; wave w owns query rows [w*16, w*16+16).
  f32x4 sacc[NJ];
#pragma unroll
  for (int jt = 0; jt < NJ; ++jt) sacc[jt] = 0.f;
#pragma unroll
  for (int kk = 0; kk < 2; ++kk) {
    bf16x8 aq = *(const bf16x8*)&Qs[(w * 16 + lm) * 72 + kk * 32 + quad * 8];
#pragma unroll
    for (int jt = 0; jt < NJ; ++jt) {
      bf16x8 bk = *(const bf16x8*)&Ks[(jt * 16 + lm) * 72 + kk * 32 + quad * 8];
      sacc[jt] = MFMA16(aq, bk, sacc[jt]);
    }
  }
  __syncthreads();  // Qs/Ks reads done; P/Vt writes may begin.

  // Softmax in registers; 1/sqrt(64) folded into the exp argument
  // (max-subtract commutes with positive scaling).
  int trow = TQ * 64 + w * 16 + quad * 4;  // + reg = global query index
  float inv_l[4];
#pragma unroll
  for (int reg = 0; reg < 4; ++reg) {
    float m_ = -3.0e38f;
#pragma unroll
    for (int jt = 0; jt < NJ; ++jt) {
      int col = jt * 16 + lm;
      if (col <= trow + reg) m_ = fmaxf(m_, sacc[jt][reg]);
    }
#pragma unroll
    for (int o = 1; o < 16; o <<= 1) m_ = fmaxf(m_, __shfl_xor(m_, o, 16));
    float s_ = 0.f;
#pragma unroll
    for (int jt = 0; jt < NJ; ++jt) {
      int col = jt * 16 + lm;
      float p = (col <= trow + reg) ? __expf(0.125f * (sacc[jt][reg] - m_)) : 0.f;
      sacc[jt][reg] = p;
      s_ += p;
    }
#pragma unroll
    for (int o = 1; o < 16; o <<= 1) s_ += __shfl_xor(s_, o, 16);
    inv_l[reg] = 1.f / s_;
  }
  // Write P (bf16, XOR-8 swizzled rows).
#pragma unroll
  for (int jt = 0; jt < NJ; ++jt) {
#pragma unroll
    for (int reg = 0; reg < 4; ++reg) {
      int m = w * 16 + quad * 4 + reg;
      int col = jt * 16 + lm;
      P[m * 256 + (col ^ ((m & 7) * 8))] = f2bf(sacc[jt][reg] * inv_l[reg]);
    }
  }
  // Stage V transposed (vector global read, swizzled scalar LDS writes).
  for (int i = tid; i < NFULL * 8; i += 256) {
    int sr = i >> 3, cs = i & 7;
    bf16x8 vv = *(const bf16x8*)&Vg[sr * 64 + cs * 8];
#pragma unroll
    for (int j = 0; j < 8; ++j) {
      int d = cs * 8 + j;
      Vt[d * 256 + (sr ^ ((d & 7) * 8))] = (u16)vv[j];
    }
  }
  __syncthreads();

  // O = P V ; wave w reads back its own 16 query rows.
  f32x4 oacc[4];
#pragma unroll
  for (int jt = 0; jt < 4; ++jt) oacc[jt] = 0.f;
#pragma unroll
  for (int ks = 0; ks < KSTEPS; ++ks) {
    int m = w * 16 + lm;
    int kc = ks * 32 + quad * 8;
    bf16x8 ap = *(const bf16x8*)&P[m * 256 + (kc ^ ((m & 7) * 8))];
#pragma unroll
    for (int jt = 0; jt < 4; ++jt) {
      int n = jt * 16 + lm;
      bf16x8 bv = *(const bf16x8*)&Vt[n * 256 + (kc ^ ((n & 7) * 8))];
      oacc[jt] = MFMA16(ap, bv, oacc[jt]);
    }
  }
  u16* Og = attnout + ((size_t)(b * 256 + TQ * 64)) * 384 + h * 64;
#pragma unroll
  for (int jt = 0; jt < 4; ++jt)
#pragma unroll
    for (int r = 0; r < 4; ++r)
      Og[(size_t)(w * 16 + quad * 4 + r) * 384 + jt * 16 + lm] = f2bf(oacc[jt][r]);
}

__global__ __launch_bounds__(256) void attn_all(const u16* __restrict__ qkv,
                                                u16* __restrict__ attnout) {
  __shared__ __attribute__((aligned(16))) unsigned char smx[65536];
  switch (blockIdx.x) {
    case 0: attn_body<0>(qkv, attnout, smx); break;
    case 1: attn_body<1>(qkv, attnout, smx); break;
    case 2: attn_body<2>(qkv, attnout, smx); break;
    default: attn_body<3>(qkv, attnout, smx); break;
  }
}

// ---------------------------------------------------------------------------
extern "C" void kernel_launch(void* const* d_in, const int* in_sizes, int n_in,
                              void* d_out, int out_size, void* d_ws, size_t ws_size,
                              hipStream_t stream) {
  const float* x = (const float*)d_in[0];
  const float* Wq = (const float*)d_in[1];
  const float* Wk = (const float*)d_in[2];
  const float* Wv = (const float*)d_in[3];
  const float* Wp = (const float*)d_in[4];
  const float* bp = (const float*)d_in[5];
  const float* W1 = (const float*)d_in[6];
  const float* b1 = (const float*)d_in[7];
  const float* W2 = (const float*)d_in[8];
  const float* b2 = (const float*)d_in[9];
  const float* g1 = (const float*)d_in[10];
  const float* be1 = (const float*)d_in[11];
  const float* g2 = (const float*)d_in[12];
  const float* be2 = (const float*)d_in[13];
  float* out = (float*)d_out;

  const int BT = 65536;  // 256*256
  char* ws = (char*)d_ws;
  // Workspace layout (ff1 aliases qkv+attnout, dead by FFN1):
  u16* qkv = (u16*)(ws);                  // 18 slabs [BT][64] = 150,994,944 B
  u16* attnout = (u16*)(ws + 150994944);  // [BT][384]  bf16   50,331,648 B
  u16* ff1 = (u16*)(ws);                  // [BT][1536] bf16  201,326,592 B
  u16* h = (u16*)(ws + 201326592);        // [BT][384]  bf16   50,331,648 B
  u16* WqkvT = (u16*)(ws + 251658240);    // [1152][384]
  u16* WpT = (u16*)(ws + 252542976);      // [384][384]
  u16* W1T = (u16*)(ws + 252837888);      // [1536][384]
  u16* W2T = (u16*)(ws + 254017536);      // [384][1536]

  // Weight transposes (bf16 cast), tiny.
  qkvT_kernel<<<576, 256, 0, stream>>>(Wq, WqkvT);
  qkvT_kernel<<<576, 256, 0, stream>>>(Wk, WqkvT + 384 * 384);
  qkvT_kernel<<<576, 256, 0, stream>>>(Wv, WqkvT + 2 * 384 * 384);
  wT_kernel<<<576, 256, 0, stream>>>(Wp, WpT, 384, 384);
  wT_kernel<<<2304, 256, 0, stream>>>(W1, W1T, 384, 1536);
  wT_kernel<<<2304, 256, 0, stream>>>(W2, W2T, 1536, 384);

  // LN1: x -> h (bf16)
  ln_kernel<<<BT / 4, 256, 0, stream>>>(x, g1, be1, h);
  // QKV: h @ Wqkv -> qkv slabs (OUT_MODE=2), grid gx=9, gy=512
  gemm_bt<0, 0, 0, 2><<<9 * 512, 256, 0, stream>>>(h, WqkvT, nullptr, nullptr,
                                                   qkv, BT, 1152, 384, 9);
  // Attention, merged: grid (TQ=4, b*h=1536)
  attn_all<<<dim3(4, 1536), 256, 0, stream>>>(qkv, attnout);
  // Proj + bias + residual(x) -> d_out (fp32), gx=3
  gemm_bt<1, 1, 0, 0><<<3 * 512, 256, 0, stream>>>(attnout, WpT, bp, x, out,
                                                   BT, 384, 384, 3);
  // LN2: d_out -> h (bf16)
  ln_kernel<<<BT / 4, 256, 0, stream>>>(out, g2, be2, h);
  // FFN1 + bias + relu -> ff1 (bf16), gx=12
  gemm_bt<1, 0, 1, 1><<<12 * 512, 256, 0, stream>>>(h, W1T, b1, nullptr, ff1,
                                                    BT, 1536, 384, 12);
  // FFN2 + bias + residual(d_out) -> d_out (fp32), gx=3
  gemm_bt<1, 1, 0, 0><<<3 * 512, 256, 0, stream>>>(ff1, W2T, b2, out, out,
                                                   BT, 384, 1536, 3);
}